// Round 5
// baseline (763.531 us; speedup 1.0000x reference)
//
#include <hip/hip_runtime.h>
#include <stdint.h>

#define AS1 __attribute__((address_space(1)))
#define AS3 __attribute__((address_space(3)))

typedef float floatx4 __attribute__((ext_vector_type(4)));
typedef __bf16 bf16x8 __attribute__((ext_vector_type(8)));
typedef unsigned short ushort8 __attribute__((ext_vector_type(8)));

__device__ __forceinline__ unsigned short f2bf(float x) {
    union { float f; unsigned int u; } v; v.f = x;
    unsigned int r = v.u + 0x7fffu + ((v.u >> 16) & 1u);   // round-to-nearest-even
    return (unsigned short)(r >> 16);
}

// ---------------- fp32 -> bf16 bulk convert (8 elems/thread/iter) ----------------
__global__ __launch_bounds__(256) void cvt_bf16_kernel(
        const float* __restrict__ in, unsigned short* __restrict__ out, long n) {
    long i = ((long)blockIdx.x * blockDim.x + threadIdx.x) * 8;
    long stride = (long)gridDim.x * blockDim.x * 8;
    for (; i < n; i += stride) {
        float4 a = *(const float4*)(in + i);
        float4 b = *(const float4*)(in + i + 4);
        ushort8 o;
        o[0] = f2bf(a.x); o[1] = f2bf(a.y); o[2] = f2bf(a.z); o[3] = f2bf(a.w);
        o[4] = f2bf(b.x); o[5] = f2bf(b.y); o[6] = f2bf(b.z); o[7] = f2bf(b.w);
        *(ushort8*)(out + i) = o;
    }
}

// ------- weight_norm(dim=0): W[i,:] = g[i]*v[i,:]/||v[i,:]|| -> bf16, scale -> fp32 -------
__global__ __launch_bounds__(256) void wn_kernel(
        const float* __restrict__ v, const float* __restrict__ g,
        unsigned short* __restrict__ W, float* __restrict__ scaleOut, int K) {
    int row = blockIdx.x;
    const float* vr = v + (size_t)row * K;
    float s = 0.f;
    for (int c = threadIdx.x; c < K; c += 256) { float x = vr[c]; s += x * x; }
    #pragma unroll
    for (int o = 32; o > 0; o >>= 1) s += __shfl_down(s, o, 64);
    __shared__ float red[4];
    __shared__ float scale_s;
    if ((threadIdx.x & 63) == 0) red[threadIdx.x >> 6] = s;
    __syncthreads();
    if (threadIdx.x == 0) {
        float sc = g[row] * rsqrtf(red[0] + red[1] + red[2] + red[3]);
        scale_s = sc;
        scaleOut[row] = sc;
    }
    __syncthreads();
    float scale = scale_s;
    unsigned short* Wr = W + (size_t)row * K;
    for (int c = threadIdx.x; c < K; c += 256) Wr[c] = f2bf(vr[c] * scale);
}

// ------- qh[b,d] = scale1[d] * sum_k qf[b,k] * v1[d, 2048+k]   (fp32, atomic partials) -------
__global__ __launch_bounds__(256) void qh_kernel(
        const float* __restrict__ qf, const float* __restrict__ v1,
        const float* __restrict__ scale1, float* __restrict__ qh) {
    const int t = threadIdx.x;
    const int dblk = blockIdx.x, ks = blockIdx.y;
    __shared__ float qs[32][128];
    for (int i = t; i < 4096; i += 256) {
        int b = i >> 7, kk = i & 127;
        qs[b][kk] = qf[b * 1024 + ks * 128 + kk];
    }
    __syncthreads();
    const int dLoc = t >> 1, khalf = t & 1;
    const int d = dblk * 128 + dLoc;
    const float* vp = v1 + (size_t)d * 3072 + 2048 + ks * 128 + khalf * 64;
    float acc[32];
    #pragma unroll
    for (int b = 0; b < 32; b++) acc[b] = 0.f;
    for (int j = 0; j < 64; j++) {
        float v = vp[j];
        const int kk = khalf * 64 + j;
        #pragma unroll
        for (int b = 0; b < 32; b++) acc[b] += v * qs[b][kk];
    }
    const float sc = scale1[d];
    #pragma unroll
    for (int b = 0; b < 32; b++) {
        float tot = acc[b] + __shfl_xor(acc[b], 1, 64);
        if (khalf == 0) atomicAdd(&qh[b * 1024 + d], sc * tot);
    }
}

// ---------------- NT GEMM: C[m,n] = sum_k A[m,k] * B[n,k]  (v5 pipeline) ----------------
// A: LDS double-buffered (2x16 KB), global_load_lds(16B) + XOR chunk swizzle, ONE barrier/iter
//    (DMA for tile it+1 issued at iter top -> drained by end-of-iter barrier = full-phase cover).
// B: fragments loaded DIRECTLY from global (L2-resident panels) into registers, prefetched one
//    FULL iteration ahead (bcur/bnext, loop unrolled x2) -> latency covered, LDS traffic halved.
// SYMM: grid.x = 10 upper-triangle 128x128 tiles; off-diagonal blocks also store transpose.
template<int QH, int RELU, int OUT_BF16, int SYMM>
__global__ __launch_bounds__(256, 3) void gemm_bt_kernel(
        const unsigned short* __restrict__ A,
        const unsigned short* __restrict__ Bm,   // [Nd, ldb] row-major bf16
        const float* __restrict__ bias,
        const float* __restrict__ qh,            // [32,1024] fp32 when QH
        void* __restrict__ Cout,
        int K, int lda, int ldb, int ldc,
        long strideA, long strideB, long strideC) {
    const int t = threadIdx.x;
    const int bz = blockIdx.z;
    int tM, tN;
    if (SYMM) {
        const int L = blockIdx.x;   // 0..9 -> (ti<=tj) pairs
        int ti, tj;
        if (L < 4)      { ti = 0; tj = L; }
        else if (L < 7) { ti = 1; tj = L - 3; }
        else if (L < 9) { ti = 2; tj = L - 5; }
        else            { ti = 3; tj = 3; }
        tM = ti * 128; tN = tj * 128;
    } else {
        tM = blockIdx.y * 128; tN = blockIdx.x * 128;
    }
    const unsigned short* Abase = A + (size_t)bz * strideA;
    const unsigned short* Bbase = Bm + (size_t)bz * strideB;

    __shared__ unsigned short As[2][128 * 64];

    const int lane = t & 63;
    const int wv = t >> 6;
    const int wm = (wv & 1) * 64;    // wave's 64x64 sub-tile
    const int wn = (wv >> 1) * 64;
    const int lr = lane & 15;        // MFMA fragment row (A: m, B: n)
    const int lk = (lane >> 4) * 8;  // fragment k element offset (B direct reads)

    // swizzled intra-row element offsets for LDS A reads (ks = 0, 1)
    const int koff0 = (((lane >> 4) + 0) ^ (lane & 7)) * 8;
    const int koff1 = (((lane >> 4) + 4) ^ (lane & 7)) * 8;

    floatx4 acc[4][4];
    const floatx4 fzero = {0.f, 0.f, 0.f, 0.f};
    #pragma unroll
    for (int i = 0; i < 4; i++)
        #pragma unroll
        for (int j = 0; j < 4; j++) acc[i][j] = fzero;

    const int rowQ = t >> 3;                          // staging: row within 32-row pass
    const int colSw = ((t & 7) ^ (rowQ & 7)) * 8;     // staging: swizzled source chunk
    const unsigned short* aSrc = Abase + (size_t)(tM + rowQ) * lda + colSw;
    const size_t aP = (size_t)32 * lda;               // 32-row stage-pass stride

    const unsigned short* bP[4];
    #pragma unroll
    for (int j = 0; j < 4; j++)
        bP[j] = Bbase + (size_t)(tN + wn + j * 16 + lr) * ldb + lk;

    const int n1 = K / 64;   // always even (32 or 16)

    // prologue: DMA A(0) -> As[0]; load B(0) -> b0
    #pragma unroll
    for (int p = 0; p < 4; p++)
        __builtin_amdgcn_global_load_lds((AS1 void*)(aSrc + p * aP),
                                         (AS3 void*)(&As[0][p * 2048 + t * 8]),
                                         16, 0, 0);
    bf16x8 b0[2][4], b1[2][4];
    #pragma unroll
    for (int ks = 0; ks < 2; ks++)
        #pragma unroll
        for (int j = 0; j < 4; j++)
            b0[ks][j] = *(const bf16x8*)(bP[j] + ks * 32);
    __syncthreads();   // drains DMA A(0) (and B(0))

    auto body = [&](int it, bf16x8 (&bc)[2][4], bf16x8 (&bn)[2][4]) {
        const int knxt = it * 64 + 64;
        if (it + 1 < n1) {
            // prefetch B(it+1) into registers (consumed next iter)
            #pragma unroll
            for (int ks = 0; ks < 2; ks++)
                #pragma unroll
                for (int j = 0; j < 4; j++)
                    bn[ks][j] = *(const bf16x8*)(bP[j] + knxt + ks * 32);
            // DMA A(it+1) into the other buffer (drained by end-of-iter barrier)
            #pragma unroll
            for (int p = 0; p < 4; p++)
                __builtin_amdgcn_global_load_lds((AS1 void*)(aSrc + p * aP + knxt),
                    (AS3 void*)(&As[(it + 1) & 1][p * 2048 + t * 8]), 16, 0, 0);
        }
        const unsigned short* asb = As[it & 1];
        #pragma unroll
        for (int ks = 0; ks < 2; ks++) {
            const int koff = ks ? koff1 : koff0;
            bf16x8 af[4];
            #pragma unroll
            for (int i = 0; i < 4; i++)
                af[i] = *(const bf16x8*)(&asb[(wm + i * 16 + lr) * 64 + koff]);
            #pragma unroll
            for (int i = 0; i < 4; i++)
                #pragma unroll
                for (int j = 0; j < 4; j++)
                    acc[i][j] = __builtin_amdgcn_mfma_f32_16x16x32_bf16(
                        af[i], bc[ks][j], acc[i][j], 0, 0, 0);
        }
        __syncthreads();   // As[it&1] read-done + drains DMA(it+1)/B(it+1)
    };

    for (int it = 0; it < n1; it += 2) {
        body(it, b0, b1);
        body(it + 1, b1, b0);
    }

    // epilogue: D row (M) = (lane>>4)*4 + r, col (N) = lane&15  [m89-verified layout]
    unsigned short* Cb = (unsigned short*)Cout + (size_t)bz * strideC;
    float* Cf = (float*)Cout + (size_t)bz * strideC;
    const float* qhr = QH ? (qh + (size_t)(tM >> 9) * 1024) : nullptr;
    const int rowHalf = (lane >> 4) * 4;
    #pragma unroll
    for (int j = 0; j < 4; j++) {
        const int col = tN + wn + j * 16 + lr;
        float bv = RELU ? bias[col] : 0.0f;
        if (QH) bv += qhr[col];
        #pragma unroll
        for (int i = 0; i < 4; i++) {
            const int row0 = tM + wm + i * 16 + rowHalf;
            float vals[4];
            #pragma unroll
            for (int r = 0; r < 4; r++) {
                float val = acc[i][j][r] + bv;
                if (RELU) val = fmaxf(val, 0.0f);
                vals[r] = val;
                const size_t off = (size_t)(row0 + r) * ldc + col;
                if (OUT_BF16) Cb[off] = f2bf(val);
                else          Cf[off] = val;
            }
            if (SYMM && tM != tN) {
                // transposed tile store: contiguous float4 per lane
                *(float4*)(&Cf[(size_t)col * ldc + row0]) =
                    make_float4(vals[0], vals[1], vals[2], vals[3]);
            }
        }
    }
}

// ---------------- gather: out[e] = S_flat[idx[e]] ----------------
__global__ __launch_bounds__(256) void gather_kernel(
        const float* __restrict__ S, const int* __restrict__ idx,
        float* __restrict__ out, int E) {
    int e = blockIdx.x * 256 + threadIdx.x;
    if (e < E) out[e] = S[idx[e]];
}

extern "C" void kernel_launch(void* const* d_in, const int* in_sizes, int n_in,
                              void* d_out, int out_size, void* d_ws, size_t ws_size,
                              hipStream_t stream) {
    const float* node = (const float*)d_in[0];   // [32,512,2048]
    const float* qf   = (const float*)d_in[1];   // [32,1024]
    const int*   idx  = (const int*)d_in[2];     // [1048576]
    const float* v1   = (const float*)d_in[3];   // [1024,3072]
    const float* g1   = (const float*)d_in[4];
    const float* b1   = (const float*)d_in[5];
    const float* v2   = (const float*)d_in[6];   // [1024,1024]
    const float* g2   = (const float*)d_in[7];
    const float* b2   = (const float*)d_in[8];
    float* out = (float*)d_out;

    // workspace carve (all offsets 256B aligned); S aliases nodesB (dead after GEMM1)
    char* ws = (char*)d_ws;
    unsigned short* W1     = (unsigned short*)(ws);              // 6,291,456 B
    unsigned short* W2     = (unsigned short*)(ws + 6291456);    // 2,097,152 B
    unsigned short* nodesB = (unsigned short*)(ws + 8388608);    // 67,108,864 B (reused as S)
    float*          S      = (float*)(ws + 8388608);             // 33,554,432 B (alias)
    unsigned short* h1     = (unsigned short*)(ws + 75563008);   // 33,554,432 B
    unsigned short* h2     = (unsigned short*)(ws + 109117440);  // 33,554,432 B
    float*          scale1 = (float*)(ws + 142671872);           // 4,096 B
    float*          scale2 = (float*)(ws + 142675968);           // 4,096 B
    float*          qh     = (float*)(ws + 142680064);           // 131,072 B
    // total: 142,811,136 B

    // prep: bf16 conversions + weight-norm + folded q@W1b^T
    cvt_bf16_kernel<<<4096, 256, 0, stream>>>(node, nodesB, 33554432L);
    wn_kernel<<<1024, 256, 0, stream>>>(v1, g1, W1, scale1, 3072);
    wn_kernel<<<1024, 256, 0, stream>>>(v2, g2, W2, scale2, 1024);
    hipMemsetAsync(qh, 0, 131072, stream);
    qh_kernel<<<dim3(8, 8), 256, 0, stream>>>(qf, v1, scale1, qh);

    dim3 blk(256);
    // h1 = relu(nodes @ W1a^T + qh[b] + b1)    M=16384 N=1024 K=2048 (ldb=3072)
    dim3 grid1(8, 128, 1);
    gemm_bt_kernel<1, 1, 1, 0><<<grid1, blk, 0, stream>>>(
        nodesB, W1, b1, qh, h1, 2048, 2048, 3072, 1024, 0, 0, 0);
    // h2 = relu(h1 @ W2^T + b2)                M=16384 N=1024 K=1024
    gemm_bt_kernel<0, 1, 1, 0><<<grid1, blk, 0, stream>>>(
        h1, W2, b2, nullptr, h2, 1024, 1024, 1024, 1024, 0, 0, 0);
    // S[b] = h2[b] @ h2[b]^T  (symmetric: 10 triangle tiles, dual store)
    dim3 gridg(10, 1, 32);
    gemm_bt_kernel<0, 0, 0, 1><<<gridg, blk, 0, stream>>>(
        h2, h2, nullptr, nullptr, S, 1024, 1024, 1024, 512,
        512L * 1024L, 512L * 1024L, 512L * 512L);
    // gather
    gather_kernel<<<4096, 256, 0, stream>>>(S, idx, out, 1048576);
}

// Round 6
// 554.314 us; speedup vs baseline: 1.3774x; 1.3774x over previous
//
#include <hip/hip_runtime.h>
#include <stdint.h>

#define AS1 __attribute__((address_space(1)))
#define AS3 __attribute__((address_space(3)))

typedef float floatx4 __attribute__((ext_vector_type(4)));
typedef __bf16 bf16x8 __attribute__((ext_vector_type(8)));
typedef unsigned short ushort8 __attribute__((ext_vector_type(8)));

__device__ __forceinline__ unsigned short f2bf(float x) {
    union { float f; unsigned int u; } v; v.f = x;
    unsigned int r = v.u + 0x7fffu + ((v.u >> 16) & 1u);   // round-to-nearest-even
    return (unsigned short)(r >> 16);
}

// ---------------- fp32 -> bf16 bulk convert (8 elems/thread/iter) ----------------
__global__ __launch_bounds__(256) void cvt_bf16_kernel(
        const float* __restrict__ in, unsigned short* __restrict__ out, long n) {
    long i = ((long)blockIdx.x * blockDim.x + threadIdx.x) * 8;
    long stride = (long)gridDim.x * blockDim.x * 8;
    for (; i < n; i += stride) {
        float4 a = *(const float4*)(in + i);
        float4 b = *(const float4*)(in + i + 4);
        ushort8 o;
        o[0] = f2bf(a.x); o[1] = f2bf(a.y); o[2] = f2bf(a.z); o[3] = f2bf(a.w);
        o[4] = f2bf(b.x); o[5] = f2bf(b.y); o[6] = f2bf(b.z); o[7] = f2bf(b.w);
        *(ushort8*)(out + i) = o;
    }
}

// ------- weight_norm(dim=0): W[i,:] = g[i]*v[i,:]/||v[i,:]|| -> bf16, scale -> fp32 -------
__global__ __launch_bounds__(256) void wn_kernel(
        const float* __restrict__ v, const float* __restrict__ g,
        unsigned short* __restrict__ W, float* __restrict__ scaleOut, int K) {
    int row = blockIdx.x;
    const float* vr = v + (size_t)row * K;
    float s = 0.f;
    for (int c = threadIdx.x; c < K; c += 256) { float x = vr[c]; s += x * x; }
    #pragma unroll
    for (int o = 32; o > 0; o >>= 1) s += __shfl_down(s, o, 64);
    __shared__ float red[4];
    __shared__ float scale_s;
    if ((threadIdx.x & 63) == 0) red[threadIdx.x >> 6] = s;
    __syncthreads();
    if (threadIdx.x == 0) {
        float sc = g[row] * rsqrtf(red[0] + red[1] + red[2] + red[3]);
        scale_s = sc;
        scaleOut[row] = sc;
    }
    __syncthreads();
    float scale = scale_s;
    unsigned short* Wr = W + (size_t)row * K;
    for (int c = threadIdx.x; c < K; c += 256) Wr[c] = f2bf(vr[c] * scale);
}

// ------- qh[b,d] = scale1[d] * sum_k qf[b,k] * v1[d, 2048+k]   (fp32, atomic partials) -------
__global__ __launch_bounds__(256) void qh_kernel(
        const float* __restrict__ qf, const float* __restrict__ v1,
        const float* __restrict__ scale1, float* __restrict__ qh) {
    const int t = threadIdx.x;
    const int dblk = blockIdx.x, ks = blockIdx.y;
    __shared__ float qs[32][128];
    for (int i = t; i < 4096; i += 256) {
        int b = i >> 7, kk = i & 127;
        qs[b][kk] = qf[b * 1024 + ks * 128 + kk];
    }
    __syncthreads();
    const int dLoc = t >> 1, khalf = t & 1;
    const int d = dblk * 128 + dLoc;
    const float* vp = v1 + (size_t)d * 3072 + 2048 + ks * 128 + khalf * 64;
    float acc[32];
    #pragma unroll
    for (int b = 0; b < 32; b++) acc[b] = 0.f;
    for (int j = 0; j < 64; j++) {
        float v = vp[j];
        const int kk = khalf * 64 + j;
        #pragma unroll
        for (int b = 0; b < 32; b++) acc[b] += v * qs[b][kk];
    }
    const float sc = scale1[d];
    #pragma unroll
    for (int b = 0; b < 32; b++) {
        float tot = acc[b] + __shfl_xor(acc[b], 1, 64);
        if (khalf == 0) atomicAdd(&qh[b * 1024 + d], sc * tot);
    }
}

// ---------------- NT GEMM: C[m,n] = sum_k A[m,k] * B[n,k]  (v6 pipeline) ----------------
// A: LDS double-buffered (2x16 KB), global_load_lds(16B) + XOR chunk swizzle, ONE barrier/iter.
//    DMA for tile it+1 issued at iter top -> drained by end-of-iter barrier (full-phase cover).
// B: fragments loaded directly from global (L2-resident panels) into registers, prefetched one
//    full iteration ahead. Loop bodies INLINED even/odd (no lambda: reference-array params
//    blocked SROA in R5 and spilled b0/b1 to scratch -> +530 MB HBM/dispatch).
// __launch_bounds__(256) only: do NOT force 3 waves/EU; ~150 VGPR fits 3 waves naturally.
// SYMM: grid.x = 10 upper-triangle 128x128 tiles; off-diagonal blocks also store transpose.
template<int QH, int RELU, int OUT_BF16, int SYMM>
__global__ __launch_bounds__(256) void gemm_bt_kernel(
        const unsigned short* __restrict__ A,
        const unsigned short* __restrict__ Bm,   // [Nd, ldb] row-major bf16
        const float* __restrict__ bias,
        const float* __restrict__ qh,            // [32,1024] fp32 when QH
        void* __restrict__ Cout,
        int K, int lda, int ldb, int ldc,
        long strideA, long strideB, long strideC) {
    const int t = threadIdx.x;
    const int bz = blockIdx.z;
    int tM, tN;
    if (SYMM) {
        const int L = blockIdx.x;   // 0..9 -> (ti<=tj) pairs
        int ti, tj;
        if (L < 4)      { ti = 0; tj = L; }
        else if (L < 7) { ti = 1; tj = L - 3; }
        else if (L < 9) { ti = 2; tj = L - 5; }
        else            { ti = 3; tj = 3; }
        tM = ti * 128; tN = tj * 128;
    } else {
        tM = blockIdx.y * 128; tN = blockIdx.x * 128;
    }
    const unsigned short* Abase = A + (size_t)bz * strideA;
    const unsigned short* Bbase = Bm + (size_t)bz * strideB;

    __shared__ unsigned short As[2][128 * 64];

    const int lane = t & 63;
    const int wv = t >> 6;
    const int wm = (wv & 1) * 64;    // wave's 64x64 sub-tile
    const int wn = (wv >> 1) * 64;
    const int lr = lane & 15;        // MFMA fragment row (A: m, B: n)
    const int lk = (lane >> 4) * 8;  // fragment k element offset (B direct reads)

    // swizzled intra-row element offsets for LDS A reads (ks = 0, 1)
    const int koff0 = (((lane >> 4) + 0) ^ (lane & 7)) * 8;
    const int koff1 = (((lane >> 4) + 4) ^ (lane & 7)) * 8;

    floatx4 acc[4][4];
    const floatx4 fzero = {0.f, 0.f, 0.f, 0.f};
    #pragma unroll
    for (int i = 0; i < 4; i++)
        #pragma unroll
        for (int j = 0; j < 4; j++) acc[i][j] = fzero;

    const int rowQ = t >> 3;                          // staging: row within 32-row pass
    const int colSw = ((t & 7) ^ (rowQ & 7)) * 8;     // staging: swizzled source chunk
    const unsigned short* aSrc = Abase + (size_t)(tM + rowQ) * lda + colSw;
    const size_t aP = (size_t)32 * lda;               // 32-row stage-pass stride

    const unsigned short* bP[4];
    #pragma unroll
    for (int j = 0; j < 4; j++)
        bP[j] = Bbase + (size_t)(tN + wn + j * 16 + lr) * ldb + lk;

    const int n1 = K / 64;   // 32 or 16 -- always even

    bf16x8 b0[2][4], b1[2][4];
    // prologue: DMA A(0) -> As[0]; load B(0) -> b0
    #pragma unroll
    for (int p = 0; p < 4; p++)
        __builtin_amdgcn_global_load_lds((AS1 void*)(aSrc + p * aP),
                                         (AS3 void*)(&As[0][p * 2048 + t * 8]),
                                         16, 0, 0);
    #pragma unroll
    for (int ks = 0; ks < 2; ks++)
        #pragma unroll
        for (int j = 0; j < 4; j++)
            b0[ks][j] = *(const bf16x8*)(bP[j] + ks * 32);
    __syncthreads();   // drains DMA A(0)

    for (int it = 0; it < n1; it += 2) {
        // ---------- even iter: compute As[0] x b0, prefetch (it+1) -> As[1], b1 ----------
        {
            const int inx = it + 1;
            if (inx < n1) {
                #pragma unroll
                for (int ks = 0; ks < 2; ks++)
                    #pragma unroll
                    for (int j = 0; j < 4; j++)
                        b1[ks][j] = *(const bf16x8*)(bP[j] + inx * 64 + ks * 32);
                #pragma unroll
                for (int p = 0; p < 4; p++)
                    __builtin_amdgcn_global_load_lds((AS1 void*)(aSrc + p * aP + inx * 64),
                        (AS3 void*)(&As[1][p * 2048 + t * 8]), 16, 0, 0);
            }
            #pragma unroll
            for (int ks = 0; ks < 2; ks++) {
                const int koff = ks ? koff1 : koff0;
                bf16x8 af[4];
                #pragma unroll
                for (int i = 0; i < 4; i++)
                    af[i] = *(const bf16x8*)(&As[0][(wm + i * 16 + lr) * 64 + koff]);
                #pragma unroll
                for (int i = 0; i < 4; i++)
                    #pragma unroll
                    for (int j = 0; j < 4; j++)
                        acc[i][j] = __builtin_amdgcn_mfma_f32_16x16x32_bf16(
                            af[i], b0[ks][j], acc[i][j], 0, 0, 0);
            }
            __syncthreads();   // As[0] reads done; drains DMA(it+1) into As[1]
        }
        // ---------- odd iter: compute As[1] x b1, prefetch (it+2) -> As[0], b0 ----------
        {
            const int inx = it + 2;
            if (inx < n1) {
                #pragma unroll
                for (int ks = 0; ks < 2; ks++)
                    #pragma unroll
                    for (int j = 0; j < 4; j++)
                        b0[ks][j] = *(const bf16x8*)(bP[j] + inx * 64 + ks * 32);
                #pragma unroll
                for (int p = 0; p < 4; p++)
                    __builtin_amdgcn_global_load_lds((AS1 void*)(aSrc + p * aP + inx * 64),
                        (AS3 void*)(&As[0][p * 2048 + t * 8]), 16, 0, 0);
            }
            #pragma unroll
            for (int ks = 0; ks < 2; ks++) {
                const int koff = ks ? koff1 : koff0;
                bf16x8 af[4];
                #pragma unroll
                for (int i = 0; i < 4; i++)
                    af[i] = *(const bf16x8*)(&As[1][(wm + i * 16 + lr) * 64 + koff]);
                #pragma unroll
                for (int i = 0; i < 4; i++)
                    #pragma unroll
                    for (int j = 0; j < 4; j++)
                        acc[i][j] = __builtin_amdgcn_mfma_f32_16x16x32_bf16(
                            af[i], b1[ks][j], acc[i][j], 0, 0, 0);
            }
            __syncthreads();   // As[1] reads done; drains DMA(it+2) into As[0]
        }
    }

    // epilogue: D row (M) = (lane>>4)*4 + r, col (N) = lane&15  [m89-verified layout]
    unsigned short* Cb = (unsigned short*)Cout + (size_t)bz * strideC;
    float* Cf = (float*)Cout + (size_t)bz * strideC;
    const float* qhr = QH ? (qh + (size_t)(tM >> 9) * 1024) : nullptr;
    const int rowHalf = (lane >> 4) * 4;
    #pragma unroll
    for (int j = 0; j < 4; j++) {
        const int col = tN + wn + j * 16 + lr;
        float bv = RELU ? bias[col] : 0.0f;
        if (QH) bv += qhr[col];
        #pragma unroll
        for (int i = 0; i < 4; i++) {
            const int row0 = tM + wm + i * 16 + rowHalf;
            float vals[4];
            #pragma unroll
            for (int r = 0; r < 4; r++) {
                float val = acc[i][j][r] + bv;
                if (RELU) val = fmaxf(val, 0.0f);
                vals[r] = val;
                const size_t off = (size_t)(row0 + r) * ldc + col;
                if (OUT_BF16) Cb[off] = f2bf(val);
                else          Cf[off] = val;
            }
            if (SYMM && tM != tN) {
                // transposed tile store: contiguous float4 per lane
                *(float4*)(&Cf[(size_t)col * ldc + row0]) =
                    make_float4(vals[0], vals[1], vals[2], vals[3]);
            }
        }
    }
}

// ---------------- gather: out[e] = S_flat[idx[e]] ----------------
__global__ __launch_bounds__(256) void gather_kernel(
        const float* __restrict__ S, const int* __restrict__ idx,
        float* __restrict__ out, int E) {
    int e = blockIdx.x * 256 + threadIdx.x;
    if (e < E) out[e] = S[idx[e]];
}

extern "C" void kernel_launch(void* const* d_in, const int* in_sizes, int n_in,
                              void* d_out, int out_size, void* d_ws, size_t ws_size,
                              hipStream_t stream) {
    const float* node = (const float*)d_in[0];   // [32,512,2048]
    const float* qf   = (const float*)d_in[1];   // [32,1024]
    const int*   idx  = (const int*)d_in[2];     // [1048576]
    const float* v1   = (const float*)d_in[3];   // [1024,3072]
    const float* g1   = (const float*)d_in[4];
    const float* b1   = (const float*)d_in[5];
    const float* v2   = (const float*)d_in[6];   // [1024,1024]
    const float* g2   = (const float*)d_in[7];
    const float* b2   = (const float*)d_in[8];
    float* out = (float*)d_out;

    // workspace carve (all offsets 256B aligned); S aliases nodesB (dead after GEMM1)
    char* ws = (char*)d_ws;
    unsigned short* W1     = (unsigned short*)(ws);              // 6,291,456 B
    unsigned short* W2     = (unsigned short*)(ws + 6291456);    // 2,097,152 B
    unsigned short* nodesB = (unsigned short*)(ws + 8388608);    // 67,108,864 B (reused as S)
    float*          S      = (float*)(ws + 8388608);             // 33,554,432 B (alias)
    unsigned short* h1     = (unsigned short*)(ws + 75563008);   // 33,554,432 B
    unsigned short* h2     = (unsigned short*)(ws + 109117440);  // 33,554,432 B
    float*          scale1 = (float*)(ws + 142671872);           // 4,096 B
    float*          scale2 = (float*)(ws + 142675968);           // 4,096 B
    float*          qh     = (float*)(ws + 142680064);           // 131,072 B
    // total: 142,811,136 B

    // prep: bf16 conversions + weight-norm + folded q@W1b^T
    cvt_bf16_kernel<<<4096, 256, 0, stream>>>(node, nodesB, 33554432L);
    wn_kernel<<<1024, 256, 0, stream>>>(v1, g1, W1, scale1, 3072);
    wn_kernel<<<1024, 256, 0, stream>>>(v2, g2, W2, scale2, 1024);
    hipMemsetAsync(qh, 0, 131072, stream);
    qh_kernel<<<dim3(8, 8), 256, 0, stream>>>(qf, v1, scale1, qh);

    dim3 blk(256);
    // h1 = relu(nodes @ W1a^T + qh[b] + b1)    M=16384 N=1024 K=2048 (ldb=3072)
    dim3 grid1(8, 128, 1);
    gemm_bt_kernel<1, 1, 1, 0><<<grid1, blk, 0, stream>>>(
        nodesB, W1, b1, qh, h1, 2048, 2048, 3072, 1024, 0, 0, 0);
    // h2 = relu(h1 @ W2^T + b2)                M=16384 N=1024 K=1024
    gemm_bt_kernel<0, 1, 1, 0><<<grid1, blk, 0, stream>>>(
        h1, W2, b2, nullptr, h2, 1024, 1024, 1024, 1024, 0, 0, 0);
    // S[b] = h2[b] @ h2[b]^T  (symmetric: 10 triangle tiles, dual store)
    dim3 gridg(10, 1, 32);
    gemm_bt_kernel<0, 0, 0, 1><<<gridg, blk, 0, stream>>>(
        h2, h2, nullptr, nullptr, S, 1024, 1024, 1024, 512,
        512L * 1024L, 512L * 1024L, 512L * 512L);
    // gather
    gather_kernel<<<4096, 256, 0, stream>>>(S, idx, out, 1048576);
}